// Round 4
// baseline (578.160 us; speedup 1.0000x reference)
//
#include <hip/hip_runtime.h>
#include <hip/hip_bf16.h>

// R4: inputs FP32, output FP32 (reference returns jnp.float32; harness gives
// bf16-grade tolerance to permit bf16-MFMA internals).
// Fused: binary tanh-head in fp32 (route-safe, from fp32 registers) +
// both 30-label heads via bf16 MFMA (x converted RNE during staging),
// per-row hard routing in epilogue.
// d_out fp32 = [65536*2 binary | 65536*30 routed logits].

typedef short short8 __attribute__((ext_vector_type(8)));
typedef float f32x4 __attribute__((ext_vector_type(4)));

#define HDIM 1024
#define LDXE 136    // LDS row stride in bf16 elems (272 B)

// LDS byte offsets
#define XSB_OFF  0          // bf16 x chunk [64][136] = 17408 (Cout overlay after loop)
#define WTL_OFF  17408      // bf16 Wt chunk [64][136] = 17408 (rows 60..63 zero)
#define WBL_OFF  34816      // fp32 W_bin chunk [2][128] = 1024
#define BIAS_OFF 35840      // 64 f32
#define BLL_OFF  36096      // 64*2 f32
#define RTL_OFF  36608      // 64 int
#define BBL_OFF  36864      // 2 f32
#define LDS_SZ   36880

__device__ __forceinline__ unsigned f2b(float f) {   // RNE fp32->bf16 bits
    union { float f; unsigned u; } u; u.f = f;
    unsigned r = u.u + 0x7fffu + ((u.u >> 16) & 1u);
    return r >> 16;
}

__global__ __launch_bounds__(256)
void fused_kernel(const float* __restrict__ x,
                  const float* __restrict__ W_bin,
                  const float* __restrict__ b_bin,
                  const float* __restrict__ W0,
                  const float* __restrict__ b0,
                  const float* __restrict__ W1,
                  const float* __restrict__ b1,
                  float* __restrict__ outf)
{
    __shared__ __align__(16) unsigned char smem[LDS_SZ];
    short*  xsb   = (short*)(smem + XSB_OFF);
    short*  Wtl   = (short*)(smem + WTL_OFF);
    float*  wbl   = (float*)(smem + WBL_OFF);
    float*  biasl = (float*)(smem + BIAS_OFF);
    float*  bll   = (float*)(smem + BLL_OFF);
    int*    rtl   = (int*)  (smem + RTL_OFF);
    float*  bbl   = (float*)(smem + BBL_OFF);
    float*  Cout  = (float*)(smem + XSB_OFF);   // fp32 [64][68] overlay after K loop

    const int t  = threadIdx.x;
    const int wg = blockIdx.x;
    const long gr = (long)wg * 64;

    if (t < 30)      biasl[t] = b0[t];
    else if (t < 60) biasl[t] = b1[t - 30];
    else if (t < 64) biasl[t] = 0.f;
    else if (t < 66) bbl[t - 64] = b_bin[t - 64];
    // zero Wt rows 60..63 once; never overwritten afterwards
    if (t < 136) {
        unsigned* z = (unsigned*)(Wtl + 60 * LDXE);
        z[t] = 0u; z[t + 136] = 0u;
    }

    // staging/tanh map: thread -> (row r = t>>2, quad q = t&3); 8 float4 per chunk
    const int r = t >> 2;
    const int q = t & 3;
    const float4* xg = (const float4*)(x + (gr + r) * HDIM);

    // MFMA lane mapping (16x16x32): A[m=lane&15][k=quad*8+j]
    const int wv   = t >> 6;
    const int ln   = t & 63;
    const int lq   = ln >> 4;
    const int l15  = ln & 15;
    const int arow = wv * 16 + l15;

    f32x4 acc[4];
    #pragma unroll
    for (int i = 0; i < 4; ++i) acc[i] = (f32x4){0.f, 0.f, 0.f, 0.f};
    float ba0 = 0.f, ba1 = 0.f;

    for (int kc = 0; kc < HDIM; kc += 128) {
        // ---- stage x chunk: 8 float4/thread; keep fp32 in regs for tanh ----
        float4 v[8];
        const int qb = kc >> 2;
        #pragma unroll
        for (int j = 0; j < 8; ++j) v[j] = xg[qb + q + j * 4];
        #pragma unroll
        for (int j = 0; j < 8; ++j) {
            unsigned lo = f2b(v[j].x) | (f2b(v[j].y) << 16);
            unsigned hi = f2b(v[j].z) | (f2b(v[j].w) << 16);
            uint2* dst = (uint2*)(xsb + r * LDXE + (q + j * 4) * 4);
            *dst = make_uint2(lo, hi);
        }
        // ---- stage W chunk transposed+bf16: Wt[n][kk], rows 30..59 = W1 ----
        #pragma unroll
        for (int s = 0; s < 15; ++s) {
            int id = t + s * 256;            // 0..3839 over the 128x30 chunk
            int kk = id / 30, n = id - kk * 30;
            int g  = kc * 30 + id;
            Wtl[n * LDXE + kk]        = (short)f2b(W0[g]);
            Wtl[(n + 30) * LDXE + kk] = (short)f2b(W1[g]);
        }
        // ---- stage W_bin chunk fp32 [2][128] ----
        if (t < 128) {
            float2 w = ((const float2*)W_bin)[kc + t];
            wbl[t] = w.x; wbl[128 + t] = w.y;
        }
        __syncthreads();

        // ---- MFMA: each wave 16 rows x 64 cols over this K chunk ----
        #pragma unroll
        for (int ks = 0; ks < 4; ++ks) {
            short8 a = *(const short8*)(xsb + arow * LDXE + ks * 32 + lq * 8);
            #pragma unroll
            for (int nt = 0; nt < 4; ++nt) {
                short8 bf = *(const short8*)(Wtl + (nt * 16 + l15) * LDXE + ks * 32 + lq * 8);
                acc[nt] = __builtin_amdgcn_mfma_f32_16x16x32_bf16(a, bf, acc[nt], 0, 0, 0);
            }
        }

        // ---- binary head: fp32 tanh dot from the registers just loaded ----
        #pragma unroll
        for (int j = 0; j < 8; ++j) {
            const int k = (q + j * 4) * 4;
            float th0 = tanhf(v[j].x), th1 = tanhf(v[j].y);
            float th2 = tanhf(v[j].z), th3 = tanhf(v[j].w);
            ba0 = __builtin_fmaf(th0, wbl[k],     ba0);
            ba0 = __builtin_fmaf(th1, wbl[k + 1], ba0);
            ba0 = __builtin_fmaf(th2, wbl[k + 2], ba0);
            ba0 = __builtin_fmaf(th3, wbl[k + 3], ba0);
            ba1 = __builtin_fmaf(th0, wbl[128 + k],     ba1);
            ba1 = __builtin_fmaf(th1, wbl[128 + k + 1], ba1);
            ba1 = __builtin_fmaf(th2, wbl[128 + k + 2], ba1);
            ba1 = __builtin_fmaf(th3, wbl[128 + k + 3], ba1);
        }
        __syncthreads();
    }

    // binary reduce across the 4 lanes sharing a row
    ba0 += __shfl_xor(ba0, 1); ba0 += __shfl_xor(ba0, 2);
    ba1 += __shfl_xor(ba1, 1); ba1 += __shfl_xor(ba1, 2);
    if (q == 0) {
        float v0 = ba0 + bbl[0];
        float v1 = ba1 + bbl[1];
        bll[r * 2]     = v0;
        bll[r * 2 + 1] = v1;
        rtl[r] = (v1 > v0) ? 1 : 0;   // argmax, first-index-wins on tie
    }

    // C (+bias) -> Cout fp32 [64][68]; C/D layout: col=lane&15, row=quad*4+reg
    #pragma unroll
    for (int nt = 0; nt < 4; ++nt) {
        float cb = biasl[nt * 16 + l15];
        #pragma unroll
        for (int i = 0; i < 4; ++i)
            Cout[(wv * 16 + lq * 4 + i) * 68 + nt * 16 + l15] = acc[nt][i] + cb;
    }
    __syncthreads();

    // ---- fp32 outputs ----
    // binary: [B,2] fp32; bll is already [row][2] interleaved
    if (t < 128) outf[2 * gr + t] = bll[t];
    // routed logits: contiguous 1920 fp32 per WG
    float* outg = outf + 131072 + (unsigned)wg * 1920;
    #pragma unroll
    for (int it = 0; it < 8; ++it) {
        int d = t + it * 256;
        if (d < 1920) {
            int r0 = d / 30, n0 = d - r0 * 30;
            outg[d] = Cout[r0 * 68 + rtl[r0] * 30 + n0];
        }
    }
}

extern "C" void kernel_launch(void* const* d_in, const int* in_sizes, int n_in,
                              void* d_out, int out_size, void* d_ws, size_t ws_size,
                              hipStream_t stream) {
    const float* x     = (const float*)d_in[0];
    const float* W_bin = (const float*)d_in[1];
    const float* b_bin = (const float*)d_in[2];
    const float* W0    = (const float*)d_in[3];
    const float* b0    = (const float*)d_in[4];
    const float* W1    = (const float*)d_in[5];
    const float* b1    = (const float*)d_in[6];

    hipLaunchKernelGGL(fused_kernel, dim3(65536 / 64), dim3(256), 0, stream,
                       x, W_bin, b_bin, W0, b0, W1, b1, (float*)d_out);
}

// Round 5
// 399.632 us; speedup vs baseline: 1.4467x; 1.4467x over previous
//
#include <hip/hip_runtime.h>
#include <hip/hip_bf16.h>

// R5: barrier-free streaming K-loop. fp32 in, fp32 out.
// prep: Wt bf16 [64][1024] (rows 0..29=W0^T, 30..59=W1^T, 60..63=0) + wb fp32
// [2][1024] in d_ws. main: each wave owns 16 rows; A-frags built in registers
// from global fp32 (no LDS, no K-loop barriers); B-frags from L2-resident Wt;
// binary tanh-head fp32 from the same registers; routed epilogue via LDS.
// d_out fp32 = [65536*2 binary | 65536*30 routed logits].

typedef short short8 __attribute__((ext_vector_type(8)));
typedef float f32x4 __attribute__((ext_vector_type(4)));

#define HDIM 1024

__device__ __forceinline__ unsigned f2b(float f) {   // RNE fp32->bf16 bits
    union { float f; unsigned u; } u; u.f = f;
    unsigned r = u.u + 0x7fffu + ((u.u >> 16) & 1u);
    return r >> 16;
}
__device__ __forceinline__ float fast_tanh(float x) {
    // tanh(x) = 1 - 2/(2^(2*log2e*x)+1); branchless, ~3 ulp, safe for |x|<40
    float e = __builtin_amdgcn_exp2f(x * 2.8853900817779268f);
    float r = __builtin_amdgcn_rcpf(e + 1.0f);
    return __builtin_fmaf(-2.0f, r, 1.0f);
}

__global__ void prep_kernel(const float* __restrict__ W_bin,
                            const float* __restrict__ W0,
                            const float* __restrict__ W1,
                            unsigned short* __restrict__ Wt,
                            float* __restrict__ wb)
{
    int id = blockIdx.x * 256 + threadIdx.x;
    if (id < 65536) {                       // Wt[n][k] = W^T, coalesced writes
        int n = id >> 10, k = id & 1023;
        float v = (n < 30) ? W0[k * 30 + n]
                : (n < 60) ? W1[k * 30 + (n - 30)] : 0.f;
        Wt[id] = (unsigned short)f2b(v);
    } else if (id < 67584) {                // wb[h][k] = W_bin[k][h], fp32
        int j = id - 65536;
        int h = j >> 10, k = j & 1023;
        wb[j] = W_bin[k * 2 + h];
    }
}

__global__ __launch_bounds__(256, 4)
void fused_kernel(const float* __restrict__ x,
                  const float* __restrict__ b_bin,
                  const float* __restrict__ b0,
                  const float* __restrict__ b1,
                  const unsigned short* __restrict__ Wt,
                  const float* __restrict__ wb,
                  float* __restrict__ outf)
{
    __shared__ __align__(16) float Cout[64 * 68];
    __shared__ __align__(16) float wbl[2048];
    __shared__ float bll[128];
    __shared__ int   rtl[64];

    const int t  = threadIdx.x;
    const int wg = blockIdx.x;
    const long gr = (long)wg * 64;

    // stage wb [2][1024] into LDS once (broadcast reads later: conflict-free)
    {
        const float4* src = (const float4*)wb;
        float4* dst = (float4*)wbl;
        dst[t]       = src[t];
        dst[t + 256] = src[t + 256];
    }

    const int wv   = t >> 6;     // wave id: owns rows wv*16..wv*16+15
    const int l    = t & 63;
    const int q    = l >> 4;     // k-quad within MFMA frag
    const int l15  = l & 15;
    const int arow = wv * 16 + l15;
    const float* xrow = x + (gr + arow) * HDIM;
    const unsigned short* wrow = Wt + l15 * HDIM;

    f32x4 acc[4];
    #pragma unroll
    for (int i = 0; i < 4; ++i) acc[i] = (f32x4){0.f, 0.f, 0.f, 0.f};
    float ba0 = 0.f, ba1 = 0.f;

    __syncthreads();   // wbl ready; the ONLY pre-epilogue barrier

    for (int kc = 0; kc < HDIM; kc += 128) {
        // A chunk: 8 float4 (fp32) straight into registers, fragment order
        float4 v[8];
        const float4* xr4 = (const float4*)xrow;
        #pragma unroll
        for (int j = 0; j < 8; ++j)
            v[j] = xr4[(kc >> 2) + (j >> 1) * 8 + q * 2 + (j & 1)];

        #pragma unroll
        for (int ks = 0; ks < 4; ++ks) {
            float4 va = v[2 * ks], vb2 = v[2 * ks + 1];
            // A-frag: pack 8 fp32 -> 8 bf16 (RNE)
            union { short8 s; uint4 u; } af;
            af.u.x = f2b(va.x)  | (f2b(va.y)  << 16);
            af.u.y = f2b(va.z)  | (f2b(va.w)  << 16);
            af.u.z = f2b(vb2.x) | (f2b(vb2.y) << 16);
            af.u.w = f2b(vb2.z) | (f2b(vb2.w) << 16);

            // B-frags direct from global Wt (L2-resident, 16B/lane)
            const unsigned short* wp = wrow + kc + ks * 32 + q * 8;
            #pragma unroll
            for (int nt = 0; nt < 4; ++nt) {
                short8 bf = *(const short8*)(wp + nt * 16 * HDIM);
                acc[nt] = __builtin_amdgcn_mfma_f32_16x16x32_bf16(af.s, bf, acc[nt], 0, 0, 0);
            }

            // binary head: fp32 tanh dot from the same registers
            const float* w0p = wbl + kc + ks * 32 + q * 8;
            const float* w1p = w0p + HDIM;
            float th;
            th = fast_tanh(va.x);  ba0 = __builtin_fmaf(th, w0p[0], ba0); ba1 = __builtin_fmaf(th, w1p[0], ba1);
            th = fast_tanh(va.y);  ba0 = __builtin_fmaf(th, w0p[1], ba0); ba1 = __builtin_fmaf(th, w1p[1], ba1);
            th = fast_tanh(va.z);  ba0 = __builtin_fmaf(th, w0p[2], ba0); ba1 = __builtin_fmaf(th, w1p[2], ba1);
            th = fast_tanh(va.w);  ba0 = __builtin_fmaf(th, w0p[3], ba0); ba1 = __builtin_fmaf(th, w1p[3], ba1);
            th = fast_tanh(vb2.x); ba0 = __builtin_fmaf(th, w0p[4], ba0); ba1 = __builtin_fmaf(th, w1p[4], ba1);
            th = fast_tanh(vb2.y); ba0 = __builtin_fmaf(th, w0p[5], ba0); ba1 = __builtin_fmaf(th, w1p[5], ba1);
            th = fast_tanh(vb2.z); ba0 = __builtin_fmaf(th, w0p[6], ba0); ba1 = __builtin_fmaf(th, w1p[6], ba1);
            th = fast_tanh(vb2.w); ba0 = __builtin_fmaf(th, w0p[7], ba0); ba1 = __builtin_fmaf(th, w1p[7], ba1);
        }
    }

    // binary: reduce across the 4 k-quads sharing a row (lanes l, l^16, l^32)
    ba0 += __shfl_xor(ba0, 16); ba0 += __shfl_xor(ba0, 32);
    ba1 += __shfl_xor(ba1, 16); ba1 += __shfl_xor(ba1, 32);
    if (q == 0) {
        float v0 = ba0 + b_bin[0];
        float v1 = ba1 + b_bin[1];
        bll[arow * 2]     = v0;
        bll[arow * 2 + 1] = v1;
        rtl[arow] = (v1 > v0) ? 1 : 0;   // argmax, first-index-wins on tie
    }

    // C (+bias) -> Cout fp32 [64][68]; C/D layout: col=lane&15, row=quad*4+reg
    #pragma unroll
    for (int nt = 0; nt < 4; ++nt) {
        int col = nt * 16 + l15;
        float cb = (col < 30) ? b0[col] : (col < 60) ? b1[col - 30] : 0.f;
        #pragma unroll
        for (int i = 0; i < 4; ++i)
            Cout[(wv * 16 + q * 4 + i) * 68 + col] = acc[nt][i] + cb;
    }
    __syncthreads();

    // binary out: [B,2] fp32
    if (t < 128) outf[2 * gr + t] = bll[t];
    // routed logits: contiguous 1920 fp32 per WG
    float* outg = outf + 131072 + (long)wg * 1920;
    #pragma unroll
    for (int it = 0; it < 8; ++it) {
        int d = t + it * 256;
        if (d < 1920) {
            int r0 = d / 30, n0 = d - r0 * 30;
            outg[d] = Cout[r0 * 68 + rtl[r0] * 30 + n0];
        }
    }
}

extern "C" void kernel_launch(void* const* d_in, const int* in_sizes, int n_in,
                              void* d_out, int out_size, void* d_ws, size_t ws_size,
                              hipStream_t stream) {
    const float* x     = (const float*)d_in[0];
    const float* W_bin = (const float*)d_in[1];
    const float* b_bin = (const float*)d_in[2];
    const float* W0    = (const float*)d_in[3];
    const float* b0    = (const float*)d_in[4];
    const float* W1    = (const float*)d_in[5];
    const float* b1    = (const float*)d_in[6];

    unsigned short* Wt = (unsigned short*)d_ws;                  // 128 KiB
    float* wb = (float*)((char*)d_ws + 65536 * sizeof(unsigned short));

    hipLaunchKernelGGL(prep_kernel, dim3(264), dim3(256), 0, stream,
                       W_bin, W0, W1, Wt, wb);
    hipLaunchKernelGGL(fused_kernel, dim3(1024), dim3(256), 0, stream,
                       x, b_bin, b0, b1, Wt, wb, (float*)d_out);
}